// Round 14
// baseline (152.099 us; speedup 1.0000x reference)
//
#include <hip/hip_runtime.h>
#include <stdint.h>

// PlaceCellNetwork — 50 fixed-point Jacobi iterations, per-row independent.
//
// R14 = MEASUREMENT ROUND. The kernel has been invisible below the harness's
// ~42us poison-fills since R11; model (~6-8us) vs bench arithmetic (~30-40us)
// disagree by 4-6x. Fix: repeat the entire computation REPEAT=4 times
// (idempotent — identical bytes written each pass; asm memory clobber stops
// CSE/LICM collapsing passes). 4T ~ 100-160us puts pcn_kernel in top-5 WITH
// COUNTERS. Bundled safe opt: B fragments kept as two u32 words straight
// from cvt_pk/pk_max (bit_cast to h4 at the MFMA) — kills h4 element-insert
// bloat in the loop body.
//
// Formulation (R11, PASSED absmax 0.125): z' = relu(G^T z + c) as
// v_mfma_f32_16x16x16f16; M=output j (10/16), N=rows (16/tile), K=state k.
//   A[m][k]=G[k][m]: lane = m + 16*(k/4), elem = k%4
//   B[k][n]:         lane = n + 16*(k/4), elem = k%4
//   D[m][n]:         lane = n + 16*(m/4), elem = m%4  (== B's mapping)
// => D -> cvt_pkrtz -> v_pk_max -> next B, zero cross-lane movement.
// Iter 1 free (z1=relu(c)); final iter in f32 for the store; Y_j = rd_j*z_j.

typedef _Float16 h2 __attribute__((ext_vector_type(2)));
typedef _Float16 h4 __attribute__((ext_vector_type(4)));
typedef float    f4 __attribute__((ext_vector_type(4)));
typedef uint32_t u32;

constexpr int IN_DIM  = 5;
constexpr int OUT_DIM = 10;
constexpr int ITERS   = 50;
constexpr int NT      = 4;              // tiles per wave
constexpr int REPEAT  = 4;              // measurement multiplier (idempotent)
constexpr float DT = 0.05f, LBD1 = 0.005f, LBD2 = 0.005f;

#if defined(__HIP_DEVICE_COMPILE__)
  #define MFMA16(a, b, c) __builtin_amdgcn_mfma_f32_16x16x16f16((a), (b), (c), 0, 0, 0)
#else
  #define MFMA16(a, b, c) (c)           // host pass: parse-only
#endif

__device__ __forceinline__ u32 cvt_relu_pk(float a, float b) {
    // v_cvt_pkrtz_f16_f32 + v_pk_max_f16 -> one 32-bit word (2 f16 lanes)
    h2 v = __builtin_bit_cast(h2, __builtin_amdgcn_cvt_pkrtz(a, b));
    h2 z; z.x = (_Float16)0.0f; z.y = (_Float16)0.0f;
    return __builtin_bit_cast(u32, __builtin_elementwise_max(v, z));
}

__global__ __launch_bounds__(256, 4) void pcn_kernel(
    const float* __restrict__ X,    // [n, 5]
    const float* __restrict__ W,    // [10, 5]
    const float* __restrict__ Mg,   // [10, 10]
    const float* __restrict__ b,    // [10]
    float* __restrict__ out,        // [n, 10]
    int n)
{
    __shared__ float gtab[100];     // G[k][j]
    __shared__ float rdtab[OUT_DIM];

    const int tid  = threadIdx.x;
    const int lane = tid & 63;
    const int w    = tid >> 6;      // wave in block (0..3)
    const int grp  = lane >> 4;     // element group (0..3)
    const int r16  = lane & 15;     // N-index within tile
    const long base = (long)blockIdx.x * (64 * NT) + (long)w * (16 * NT);

#pragma unroll 1
    for (int rep = 0; rep < REPEAT; ++rep) {
        asm volatile("" ::: "memory");   // force full re-execution per pass

        // ---- build G (f32) + rd in LDS (identical values each pass) ----
        if (tid < 100) {
            int k = tid / 10, j = tid % 10;
            float rdk = 1.0f / (LBD2 + Mg[k * 10 + k]);
            float rdj = 1.0f / (LBD2 + Mg[j * 10 + j]);
            gtab[tid] = (k == j) ? (1.0f - DT) * rdj : -DT * rdk * Mg[k * 10 + j];
            if (tid < OUT_DIM) rdtab[tid] = rdj;
        }
        __syncthreads();

        // ---- A fragment: A[m][k] = G[k][m]; lane m=r16, k=grp*4+e ----
        h4 afrag;
#pragma unroll
        for (int e = 0; e < 4; ++e) {
            int k = grp * 4 + e;
            float g = (k < OUT_DIM && r16 < OUT_DIM) ? gtab[k * 10 + r16] : 0.0f;
            afrag[e] = (_Float16)g;
        }

        // ---- per-lane epilogue scales ----
        float rdv[4];
#pragma unroll
        for (int e = 0; e < 4; ++e) {
            int j = grp * 4 + e;
            rdv[e] = (j < OUT_DIM) ? rdtab[j] : 0.0f;
        }

        // ---- per-tile c fragments (C operand) ----
        f4 cf[NT];
#pragma unroll
        for (int t = 0; t < NT; ++t) {
            long r = base + t * 16 + r16;
            float x[IN_DIM];
            if (r < n) {
#pragma unroll
                for (int d = 0; d < IN_DIM; ++d) x[d] = X[r * IN_DIM + d];
            } else {
#pragma unroll
                for (int d = 0; d < IN_DIM; ++d) x[d] = 0.0f;
            }
#pragma unroll
            for (int e = 0; e < 4; ++e) {
                int j = grp * 4 + e;
                if (j < OUT_DIM) {
                    float s = -b[j];
#pragma unroll
                    for (int d = 0; d < IN_DIM; ++d) s = fmaf(x[d], W[j * IN_DIM + d], s);
                    cf[t][e] = fmaf(DT, s, -LBD1);
                } else {
                    cf[t][e] = 0.0f;
                }
            }
        }

        // ---- iteration 1 free: z1 = relu(c) ----
        u32 Blo[NT], Bhi[NT];
#pragma unroll
        for (int t = 0; t < NT; ++t) {
            Blo[t] = cvt_relu_pk(cf[t][0], cf[t][1]);
            Bhi[t] = cvt_relu_pk(cf[t][2], cf[t][3]);
        }

        // ---- iterations 2..49: two-phase body ----
#pragma unroll 1
        for (int it = 0; it < ITERS - 2; ++it) {
            f4 acc[NT];
#pragma unroll
            for (int t = 0; t < NT; ++t) {
                uint2 bw; bw.x = Blo[t]; bw.y = Bhi[t];
                acc[t] = MFMA16(afrag, __builtin_bit_cast(h4, bw), cf[t]);
            }
#pragma unroll
            for (int t = 0; t < NT; ++t) {
                Blo[t] = cvt_relu_pk(acc[t][0], acc[t][1]);
                Bhi[t] = cvt_relu_pk(acc[t][2], acc[t][3]);
            }
        }

        // ---- iteration 50 in f32 + scaled store ----
#pragma unroll
        for (int t = 0; t < NT; ++t) {
            uint2 bw; bw.x = Blo[t]; bw.y = Bhi[t];
            f4 acc = MFMA16(afrag, __builtin_bit_cast(h4, bw), cf[t]);
            long r = base + t * 16 + r16;
            if (r < n) {
                float y0 = fmaxf(acc[0], 0.0f) * rdv[0];
                float y1 = fmaxf(acc[1], 0.0f) * rdv[1];
                float y2 = fmaxf(acc[2], 0.0f) * rdv[2];
                float y3 = fmaxf(acc[3], 0.0f) * rdv[3];
                float* o = out + r * OUT_DIM + grp * 4;
                if (grp < 2) {
                    *(float2*)(o)     = make_float2(y0, y1);
                    *(float2*)(o + 2) = make_float2(y2, y3);
                } else if (grp == 2) {
                    *(float2*)(o)     = make_float2(y0, y1);
                }
            }
        }
        __syncthreads();    // protect LDS before next pass rebuilds it
    }
}

extern "C" void kernel_launch(void* const* d_in, const int* in_sizes, int n_in,
                              void* d_out, int out_size, void* d_ws, size_t ws_size,
                              hipStream_t stream) {
    const float* X = (const float*)d_in[0];
    const float* W = (const float*)d_in[1];
    const float* M = (const float*)d_in[2];
    const float* b = (const float*)d_in[3];
    float* out = (float*)d_out;

    int n = in_sizes[0] / IN_DIM;           // 500000 rows
    int rows_per_block = 64 * NT;           // 4 waves x 4 tiles x 16 rows = 256
    int grid = (n + rows_per_block - 1) / rows_per_block;
    pcn_kernel<<<grid, 256, 0, stream>>>(X, W, M, b, out, n);
}

// Round 15
// 92.443 us; speedup vs baseline: 1.6453x; 1.6453x over previous
//
#include <hip/hip_runtime.h>
#include <stdint.h>

// PlaceCellNetwork — 50 fixed-point Jacobi iterations, per-row independent.
//
// R15 = R14 minus the REPEAT=4 measurement loop, plus structural fixes from
// the R14 counter readout (first real counters since R10):
//   per-pass kernel ~26us, MfmaUtil 40%, VALUBusy 61%, VGPR=36.
//   VALU-cycle back-count shows ~2.5x instruction inflation in the loop —
//   consistent with the two-phase acc[4] array being parked in AGPRs
//   (v_accvgpr_read x4/tile/iter) and/or MFMA->VALU hazard stalls.
// Fixes:
//   - single-phase body: mfma -> repack immediately per tile (acc live range
//     ~3 insts, no reason to AGPR it)
//   - unroll 2 iterations: 8-MFMA scheduling window for cross-tile/iter
//     latency cover
//   - int32 addressing
// Proven keeper from R14: B fragments as two u32 words straight out of
// cvt_pkrtz/pk_max (1.65x: R13 43.7us -> R14 26us/pass).
//
// Formulation (PASSED since R11, absmax 0.125): z' = relu(G^T z + c) as
// v_mfma_f32_16x16x16f16; M=output j (10/16), N=rows (16/tile), K=state k.
//   A[m][k]=G[k][m]: lane = m + 16*(k/4), elem = k%4
//   B[k][n]:         lane = n + 16*(k/4), elem = k%4
//   D[m][n]:         lane = n + 16*(m/4), elem = m%4  (== B's mapping)
// => D -> cvt_pkrtz -> v_pk_max -> next B, zero cross-lane movement.
// Iter 1 free (z1=relu(c)); final iter in f32 for the store; Y_j = rd_j*z_j.

typedef _Float16 h2 __attribute__((ext_vector_type(2)));
typedef _Float16 h4 __attribute__((ext_vector_type(4)));
typedef float    f4 __attribute__((ext_vector_type(4)));
typedef uint32_t u32;

constexpr int IN_DIM  = 5;
constexpr int OUT_DIM = 10;
constexpr int ITERS   = 50;
constexpr int NT      = 4;              // tiles per wave
constexpr float DT = 0.05f, LBD1 = 0.005f, LBD2 = 0.005f;

#if defined(__HIP_DEVICE_COMPILE__)
  #define MFMA16(a, b, c) __builtin_amdgcn_mfma_f32_16x16x16f16((a), (b), (c), 0, 0, 0)
#else
  #define MFMA16(a, b, c) (c)           // host pass: parse-only
#endif

__device__ __forceinline__ u32 cvt_relu_pk(float a, float b) {
    // v_cvt_pkrtz_f16_f32 + v_pk_max_f16 -> one 32-bit word (2 f16 lanes)
    h2 v = __builtin_bit_cast(h2, __builtin_amdgcn_cvt_pkrtz(a, b));
    h2 z; z.x = (_Float16)0.0f; z.y = (_Float16)0.0f;
    return __builtin_bit_cast(u32, __builtin_elementwise_max(v, z));
}

__global__ __launch_bounds__(256, 4) void pcn_kernel(
    const float* __restrict__ X,    // [n, 5]
    const float* __restrict__ W,    // [10, 5]
    const float* __restrict__ Mg,   // [10, 10]
    const float* __restrict__ b,    // [10]
    float* __restrict__ out,        // [n, 10]
    int n)
{
    __shared__ float gtab[100];     // G[k][j]
    __shared__ float rdtab[OUT_DIM];

    const int tid  = threadIdx.x;
    if (tid < 100) {
        int k = tid / 10, j = tid % 10;
        float rdk = 1.0f / (LBD2 + Mg[k * 10 + k]);
        float rdj = 1.0f / (LBD2 + Mg[j * 10 + j]);
        gtab[tid] = (k == j) ? (1.0f - DT) * rdj : -DT * rdk * Mg[k * 10 + j];
        if (tid < OUT_DIM) rdtab[tid] = rdj;
    }
    __syncthreads();

    const int lane = tid & 63;
    const int w    = tid >> 6;      // wave in block (0..3)
    const int grp  = lane >> 4;     // element group (0..3)
    const int r16  = lane & 15;     // N-index within tile
    const int base = blockIdx.x * (64 * NT) + w * (16 * NT);

    // ---- A fragment: A[m][k] = G[k][m]; lane m=r16, k=grp*4+e ----
    h4 afrag;
#pragma unroll
    for (int e = 0; e < 4; ++e) {
        int k = grp * 4 + e;
        float g = (k < OUT_DIM && r16 < OUT_DIM) ? gtab[k * 10 + r16] : 0.0f;
        afrag[e] = (_Float16)g;
    }

    // ---- per-lane epilogue scales ----
    float rdv[4];
#pragma unroll
    for (int e = 0; e < 4; ++e) {
        int j = grp * 4 + e;
        rdv[e] = (j < OUT_DIM) ? rdtab[j] : 0.0f;
    }

    // ---- per-tile c fragments (C operand) ----
    f4 cf[NT];
#pragma unroll
    for (int t = 0; t < NT; ++t) {
        int r = base + t * 16 + r16;
        float x[IN_DIM];
        if (r < n) {
#pragma unroll
            for (int d = 0; d < IN_DIM; ++d) x[d] = X[r * IN_DIM + d];
        } else {
#pragma unroll
            for (int d = 0; d < IN_DIM; ++d) x[d] = 0.0f;
        }
#pragma unroll
        for (int e = 0; e < 4; ++e) {
            int j = grp * 4 + e;
            if (j < OUT_DIM) {
                float s = -b[j];
#pragma unroll
                for (int d = 0; d < IN_DIM; ++d) s = fmaf(x[d], W[j * IN_DIM + d], s);
                cf[t][e] = fmaf(DT, s, -LBD1);
            } else {
                cf[t][e] = 0.0f;    // padding stays exactly 0
            }
        }
    }

    // ---- iteration 1 free: z1 = relu(c) ----
    u32 Blo[NT], Bhi[NT];
#pragma unroll
    for (int t = 0; t < NT; ++t) {
        Blo[t] = cvt_relu_pk(cf[t][0], cf[t][1]);
        Bhi[t] = cvt_relu_pk(cf[t][2], cf[t][3]);
    }

    // ---- iterations 2..49: single-phase per-tile body, unroll 2 ----
    // (ITERS-2 = 48 transitions, even)
#pragma unroll 2
    for (int it = 0; it < ITERS - 2; ++it) {
#pragma unroll
        for (int t = 0; t < NT; ++t) {
            uint2 bw; bw.x = Blo[t]; bw.y = Bhi[t];
            f4 acc = MFMA16(afrag, __builtin_bit_cast(h4, bw), cf[t]);
            Blo[t] = cvt_relu_pk(acc[0], acc[1]);
            Bhi[t] = cvt_relu_pk(acc[2], acc[3]);
        }
    }

    // ---- iteration 50 in f32 + scaled store: Y[r][j] = rd_j * z_j ----
#pragma unroll
    for (int t = 0; t < NT; ++t) {
        uint2 bw; bw.x = Blo[t]; bw.y = Bhi[t];
        f4 acc = MFMA16(afrag, __builtin_bit_cast(h4, bw), cf[t]);
        int r = base + t * 16 + r16;
        if (r < n) {
            float y0 = fmaxf(acc[0], 0.0f) * rdv[0];
            float y1 = fmaxf(acc[1], 0.0f) * rdv[1];
            float y2 = fmaxf(acc[2], 0.0f) * rdv[2];
            float y3 = fmaxf(acc[3], 0.0f) * rdv[3];
            float* o = out + r * OUT_DIM + grp * 4;
            if (grp < 2) {                    // j 0-3 / 4-7
                *(float2*)(o)     = make_float2(y0, y1);
                *(float2*)(o + 2) = make_float2(y2, y3);
            } else if (grp == 2) {            // j 8-9
                *(float2*)(o)     = make_float2(y0, y1);
            }                                  // grp==3: nothing
        }
    }
}

extern "C" void kernel_launch(void* const* d_in, const int* in_sizes, int n_in,
                              void* d_out, int out_size, void* d_ws, size_t ws_size,
                              hipStream_t stream) {
    const float* X = (const float*)d_in[0];
    const float* W = (const float*)d_in[1];
    const float* M = (const float*)d_in[2];
    const float* b = (const float*)d_in[3];
    float* out = (float*)d_out;

    int n = in_sizes[0] / IN_DIM;           // 500000 rows
    int rows_per_block = 64 * NT;           // 4 waves x 4 tiles x 16 rows = 256
    int grid = (n + rows_per_block - 1) / rows_per_block;
    pcn_kernel<<<grid, 256, 0, stream>>>(X, W, M, b, out, n);
}